// Round 2
// baseline (753.820 us; speedup 1.0000x reference)
//
#include <hip/hip_runtime.h>

#define NELEM 131072
#define BSETS 32768
#define DIM 128
#define HID 64
#define MAXP 17

typedef __attribute__((ext_vector_type(8))) short short8;
typedef __attribute__((ext_vector_type(4))) float f32x4;

__device__ __forceinline__ unsigned short f2bf(float f) {
  unsigned u = __float_as_uint(f);
  u += 0x7fff + ((u >> 16) & 1);   // RNE
  return (unsigned short)(u >> 16);
}

// ---------------- segment bounds from sorted batch (int32 input!) ----------------
__global__ __launch_bounds__(256) void k_bounds(const int* __restrict__ batch,
                                                int* __restrict__ start) {
  int i = blockIdx.x * 256 + threadIdx.x;
  int b = batch[i];
  if (i == 0) {
    for (int bb = 0; bb <= b; ++bb) start[bb] = 0;
  } else {
    int bp = batch[i - 1];
    for (int bb = bp + 1; bb <= b; ++bb) start[bb] = i;
  }
  if (i == NELEM - 1) {
    for (int bb = b + 1; bb <= BSETS; ++bb) start[bb] = NELEM;
  }
}

// ---------------- rank scores (fp64 for ordering robustness) ----------------
__global__ __launch_bounds__(256) void k_mag(const float* __restrict__ x,
                                             const float* __restrict__ rank_w,
                                             const float* __restrict__ rank_b,
                                             double* __restrict__ mag) {
  int i = blockIdx.x * 256 + threadIdx.x;
  const float* xr = x + (size_t)i * DIM;
  double acc = 0.0;
#pragma unroll 8
  for (int k = 0; k < DIM; ++k) acc += (double)xr[k] * (double)rank_w[k];
  mag[i] = acc + (double)rank_b[0];
}

// ---------------- rank within segment (stable ascending) ----------------
__global__ __launch_bounds__(256) void k_rank(const int* __restrict__ batch,
                                              const int* __restrict__ start,
                                              const double* __restrict__ mag,
                                              int* __restrict__ key) {
  int i = blockIdx.x * 256 + threadIdx.x;
  int b = batch[i];
  int s = start[b], e = start[b + 1];
  double mi = mag[i];
  int r = 0;
  for (int j = s; j < e; ++j) {
    double mj = mag[j];
    r += (mj < mi) || (mj == mi && j < i);
  }
  key[i] = r;
}

// ---------------- positional-encoder tables (17->40 LN tanh ->64) ----------------
__device__ void pos_mlp40(int row, const float* w1, const float* b1, const float* g,
                          const float* bt, const float* w2, const float* b2, float* out) {
  float h[40];
  for (int j = 0; j < 40; ++j) h[j] = b1[j] + (row >= 0 ? w1[row * 40 + j] : 0.0f);
  float s = 0.f;
  for (int j = 0; j < 40; ++j) s += h[j];
  float mean = s * (1.0f / 40.0f);
  float v = 0.f;
  for (int j = 0; j < 40; ++j) { float d = h[j] - mean; v += d * d; }
  float rs = rsqrtf(v * (1.0f / 40.0f) + 1e-5f);
  float tb[40];
  for (int j = 0; j < 40; ++j) tb[j] = tanhf((h[j] - mean) * rs * g[j] + bt[j]);
  for (int o = 0; o < 64; ++o) {
    float a = b2[o];
    for (int j = 0; j < 40; ++j) a += tb[j] * w2[j * 64 + o];
    out[o] = a;
  }
}

__global__ void k_tables(const float* ew1, const float* eb1, const float* eg, const float* ebt,
                         const float* ew2, const float* eb2,
                         const float* dw1, const float* db1, const float* dg, const float* dbt,
                         const float* dw2, const float* db2,
                         float* enc_tab, float* dec_tab) {
  int t = threadIdx.x;
  if (t < 18) {                      // rows 0..16 one-hot, row 17 = zero input (key>=17)
    float out[64];
    pos_mlp40(t < 17 ? t : -1, ew1, eb1, eg, ebt, ew2, eb2, out);
    for (int o = 0; o < 64; ++o) enc_tab[t * 64 + o] = out[o];
  } else if (t >= 32 && t < 49) {    // decoder pe rows 0..16
    float out[64];
    pos_mlp40(t - 32, dw1, db1, dg, dbt, dw2, db2, out);
    for (int o = 0; o < 64; ++o) dec_tab[(t - 32) * 64 + o] = out[o];
  }
}

// ---------------- decoder weights -> bf16, MFMA-fragment-swizzled ----------------
// layout: [(kstep*NT + ntile)*64 + lane]*8 + i  holds  W[k = kstep*32 + (lane>>4)*8 + i][n = ntile*16 + (lane&15)]
__global__ __launch_bounds__(256) void k_prep_w(const float* __restrict__ w1,
                                                const float* __restrict__ w2,
                                                unsigned short* __restrict__ w1s,
                                                unsigned short* __restrict__ w2s) {
  int idx = blockIdx.x * 256 + threadIdx.x;
  if (idx < 6144) {   // dec_w1: 64x96, 2 ksteps x 6 ntiles
    int i = idx & 7, lane = (idx >> 3) & 63, rest = idx >> 9;
    int jt = rest % 6, s = rest / 6;
    int k = s * 32 + (lane >> 4) * 8 + i;
    int n = jt * 16 + (lane & 15);
    w1s[idx] = f2bf(w1[k * 96 + n]);
  }
  int idx2 = idx - 6144;
  if (idx2 >= 0 && idx2 < 12288) {  // dec_w2: 96x128, 3 ksteps x 8 ntiles
    int i = idx2 & 7, lane = (idx2 >> 3) & 63, rest = idx2 >> 9;
    int jt = rest % 8, s = rest / 8;
    int k = s * 32 + (lane >> 4) * 8 + i;
    int n = jt * 16 + (lane & 15);
    w2s[idx2] = f2bf(w2[k * 128 + n]);
  }
}

// ---------------- encoder: psi MLP (128->96 LN tanh ->64) * pe[rank], scattered to sorted pos ----------------
__global__ __launch_bounds__(256) void k_encoder(
    const float* __restrict__ x, const int* __restrict__ batch,
    const int* __restrict__ key, const int* __restrict__ start,
    const float* __restrict__ w1, const float* __restrict__ b1,
    const float* __restrict__ g, const float* __restrict__ bt,
    const float* __restrict__ w2, const float* __restrict__ b2,
    const float* __restrict__ enc_tab, float* __restrict__ y1) {
  __shared__ float xt[64][129];     // x tile, padded
  __shared__ float tt[64][97];      // tanh(LN(h)) tile
  __shared__ float ps1[4][64];
  __shared__ float ps2[4][64];
  int t = threadIdx.x;
  int base = blockIdx.x * 64;
  const float4* xg = (const float4*)(x + (size_t)base * DIM);
#pragma unroll
  for (int v = 0; v < 8; ++v) {     // coalesced stage of 64x128 f32
    int f = t + 256 * v;
    float4 val = xg[f];
    int e = f >> 5, kq = (f & 31) * 4;
    xt[e][kq] = val.x; xt[e][kq + 1] = val.y; xt[e][kq + 2] = val.z; xt[e][kq + 3] = val.w;
  }
  __syncthreads();
  int lane = t & 63;
  int w = __builtin_amdgcn_readfirstlane(t >> 6);   // wave id -> scalar (uniform weight idx)
  int j0 = w * 24;                                  // layer1: each wave 24 of 96 hidden
  float acc[24];
#pragma unroll
  for (int jj = 0; jj < 24; ++jj) acc[jj] = b1[j0 + jj];
  for (int k = 0; k < DIM; ++k) {
    float xv = xt[lane][k];
#pragma unroll
    for (int jj = 0; jj < 24; ++jj) acc[jj] += xv * w1[k * 96 + j0 + jj];
  }
  float s1 = 0.f, s2 = 0.f;
#pragma unroll
  for (int jj = 0; jj < 24; ++jj) { s1 += acc[jj]; s2 += acc[jj] * acc[jj]; }
  ps1[w][lane] = s1; ps2[w][lane] = s2;
  __syncthreads();
  float S1 = ps1[0][lane] + ps1[1][lane] + ps1[2][lane] + ps1[3][lane];
  float S2 = ps2[0][lane] + ps2[1][lane] + ps2[2][lane] + ps2[3][lane];
  float mean = S1 * (1.0f / 96.0f);
  float var = S2 * (1.0f / 96.0f) - mean * mean;
  float rs = rsqrtf(var + 1e-5f);
#pragma unroll
  for (int jj = 0; jj < 24; ++jj) {
    float hv = (acc[jj] - mean) * rs * g[j0 + jj] + bt[j0 + jj];
    tt[lane][j0 + jj] = tanhf(hv);
  }
  __syncthreads();
  int o0 = w * 16;                                  // layer2: each wave 16 of 64 outputs
  float acc2[16];
#pragma unroll
  for (int oo = 0; oo < 16; ++oo) acc2[oo] = b2[o0 + oo];
  for (int j = 0; j < 96; ++j) {
    float tv = tt[lane][j];
#pragma unroll
    for (int oo = 0; oo < 16; ++oo) acc2[oo] += tv * w2[j * 64 + o0 + oo];
  }
  int gi = base + lane;
  int kk = key[gi];
  int row = kk < MAXP ? kk : MAXP;                  // key>=17 -> zero-input table row
  int bb = batch[gi];
  int pos = start[bb] + kk;                         // sorted position
  const float* pe = enc_tab + row * 64;
#pragma unroll
  for (int oo = 0; oo < 16; ++oo) acc2[oo] *= pe[o0 + oo];
  float4* d4 = (float4*)(y1 + (size_t)pos * 64 + o0);
#pragma unroll
  for (int q = 0; q < 4; ++q)
    d4[q] = make_float4(acc2[4 * q], acc2[4 * q + 1], acc2[4 * q + 2], acc2[4 * q + 3]);
}

// ---------------- deterministic per-segment sum in sorted (index) order ----------------
__global__ __launch_bounds__(256) void k_segsum(const float* __restrict__ y1,
                                                const int* __restrict__ start,
                                                float* __restrict__ y2) {
  int idx = blockIdx.x * 256 + threadIdx.x;   // B*64 threads
  int b = idx >> 6, o = idx & 63;
  int s = start[b], e = start[b + 1];
  float acc = 0.f;
  for (int p = s; p < e; ++p) acc += y1[(size_t)p * 64 + o];
  y2[idx] = acc;
}

// ---------------- phi MLP + size_pred + argmax (fp32) ----------------
__global__ __launch_bounds__(256) void k_phi(const float* __restrict__ y2,
                                             const int* __restrict__ start,
                                             const float* __restrict__ w1, const float* __restrict__ b1,
                                             const float* __restrict__ w2, const float* __restrict__ b2,
                                             const float* __restrict__ sw1, const float* __restrict__ sb1,
                                             const float* __restrict__ sw2, const float* __restrict__ sb2,
                                             float* __restrict__ z, int* __restrict__ ndec) {
  int b = blockIdx.x * 256 + threadIdx.x;
  int nb = start[b + 1] - start[b];
  float h[72];
#pragma unroll
  for (int j = 0; j < 72; ++j) h[j] = b1[j];
  const float* yr = y2 + (size_t)b * 64;
  for (int k = 0; k < 64; ++k) {
    float yv = yr[k];
#pragma unroll
    for (int j = 0; j < 72; ++j) h[j] += yv * w1[k * 72 + j];
  }
  if (nb < MAXP) {                      // one-hot(n) row; n>=17 -> zero one-hot
    const float* wr = w1 + (64 + nb) * 72;
#pragma unroll
    for (int j = 0; j < 72; ++j) h[j] += wr[j];
  }
#pragma unroll
  for (int j = 0; j < 72; ++j) h[j] = tanhf(h[j]);
  float zv[64];
#pragma unroll
  for (int o = 0; o < 64; ++o) zv[o] = b2[o];
  for (int j = 0; j < 72; ++j) {
    float tv = h[j];
#pragma unroll
    for (int o = 0; o < 64; ++o) zv[o] += tv * w2[j * 64 + o];
  }
  float* zr = z + (size_t)b * 64;
#pragma unroll
  for (int o = 0; o < 64; ++o) zr[o] = zv[o];
  float hs[40];
#pragma unroll
  for (int j = 0; j < 40; ++j) hs[j] = sb1[j];
  for (int o = 0; o < 64; ++o) {
    float v = zv[o];
#pragma unroll
    for (int j = 0; j < 40; ++j) hs[j] += v * sw1[o * 40 + j];
  }
  float lg[17];
#pragma unroll
  for (int l = 0; l < 17; ++l) lg[l] = sb2[l];
  for (int j = 0; j < 40; ++j) {
    float tv = tanhf(hs[j]);
#pragma unroll
    for (int l = 0; l < 17; ++l) lg[l] += tv * sw2[j * 17 + l];
  }
  float best = lg[0]; int bi = 0;
#pragma unroll
  for (int l = 1; l < 17; ++l) if (lg[l] > best) { best = lg[l]; bi = l; }
  ndec[b] = bi;
}

// ---------------- decoder: zp(64) -> 96 tanh -> 128, bf16 MFMA, 64 rows/block ----------------
__global__ __launch_bounds__(256) void k_decoder(
    const float* __restrict__ z, const float* __restrict__ dec_tab,
    const unsigned short* __restrict__ w1s, const unsigned short* __restrict__ w2s,
    const float* __restrict__ b1, const float* __restrict__ b2,
    const int* __restrict__ ndec, float* __restrict__ out0) {
  __shared__ __align__(16) unsigned short h2[64][104];   // 208B row stride keeps 16B align
  int t = threadIdx.x;
  int lane = t & 63;
  int w = __builtin_amdgcn_readfirstlane(t >> 6);        // wave = m-tile
  int quad = lane >> 4, m = lane & 15;
  int r = blockIdx.x * 64 + w * 16 + m;
  int b = r / 17, p = r - b * 17;
  const float* zr = z + (size_t)b * 64;
  const float* per = dec_tab + p * 64;
  // A1 fragment: A[m=lane&15][k=quad*8+i (+32*s)], zp computed on the fly
  short8 a1[2];
#pragma unroll
  for (int s = 0; s < 2; ++s) {
    int k0 = s * 32 + quad * 8;
#pragma unroll
    for (int i = 0; i < 8; ++i) {
      float v = zr[k0 + i] * per[k0 + i];
      ((unsigned short*)&a1[s])[i] = f2bf(v);
    }
  }
  const short8* w1f = (const short8*)w1s;
  f32x4 acc[6] = {};
#pragma unroll
  for (int jt = 0; jt < 6; ++jt) {
    acc[jt] = __builtin_amdgcn_mfma_f32_16x16x32_bf16(a1[0], w1f[jt * 64 + lane], acc[jt], 0, 0, 0);
    acc[jt] = __builtin_amdgcn_mfma_f32_16x16x32_bf16(a1[1], w1f[(6 + jt) * 64 + lane], acc[jt], 0, 0, 0);
  }
  // bias + tanh, C-layout (col=lane&15,row=quad*4+reg) -> LDS in A-operand layout
#pragma unroll
  for (int jt = 0; jt < 6; ++jt) {
    int col = jt * 16 + m;
    float bias = b1[col];
#pragma unroll
    for (int reg = 0; reg < 4; ++reg) {
      int rl = w * 16 + quad * 4 + reg;
      h2[rl][col] = f2bf(tanhf(acc[jt][reg] + bias));
    }
  }
  __syncthreads();
  short8 a2[3];
#pragma unroll
  for (int s = 0; s < 3; ++s)
    a2[s] = *(const short8*)&h2[w * 16 + m][s * 32 + quad * 8];
  const short8* w2f = (const short8*)w2s;
  f32x4 acc2[8] = {};
#pragma unroll
  for (int nt = 0; nt < 8; ++nt) {
#pragma unroll
    for (int s = 0; s < 3; ++s)
      acc2[nt] = __builtin_amdgcn_mfma_f32_16x16x32_bf16(a2[s], w2f[(s * 8 + nt) * 64 + lane], acc2[nt], 0, 0, 0);
  }
#pragma unroll
  for (int nt = 0; nt < 8; ++nt) {
    int n = nt * 16 + m;
    float bias = b2[n];
#pragma unroll
    for (int reg = 0; reg < 4; ++reg) {
      int rl = w * 16 + quad * 4 + reg;
      int rg = blockIdx.x * 64 + rl;
      int bb = rg / 17, pp = rg - bb * 17;
      float v = acc2[nt][reg] + bias;
      if (pp >= ndec[bb]) v = 0.0f;
      out0[(size_t)rg * 128 + n] = v;
    }
  }
}

// ---------------- aux outputs: batchr (float), mask (0/1 float) ----------------
__global__ __launch_bounds__(256) void k_outaux(const int* __restrict__ ndec,
                                                float* __restrict__ out1,
                                                float* __restrict__ out2) {
  int r = blockIdx.x * 256 + threadIdx.x;
  int b = r / 17, p = r - b * 17;
  out1[r] = (float)b;
  out2[r] = (p < ndec[b]) ? 1.0f : 0.0f;
}

extern "C" void kernel_launch(void* const* d_in, const int* in_sizes, int n_in,
                              void* d_out, int out_size, void* d_ws, size_t ws_size,
                              hipStream_t stream) {
  const float* x = (const float*)d_in[0];
  const int* batch = (const int*)d_in[1];          // int32 per harness convention
  const float* rank_w = (const float*)d_in[2];
  const float* rank_b = (const float*)d_in[3];
  const float* psi_w1 = (const float*)d_in[4];
  const float* psi_b1 = (const float*)d_in[5];
  const float* psi_g = (const float*)d_in[6];
  const float* psi_bt = (const float*)d_in[7];
  const float* psi_w2 = (const float*)d_in[8];
  const float* psi_b2 = (const float*)d_in[9];
  const float* pe_e_w1 = (const float*)d_in[10];
  const float* pe_e_b1 = (const float*)d_in[11];
  const float* pe_e_g = (const float*)d_in[12];
  const float* pe_e_bt = (const float*)d_in[13];
  const float* pe_e_w2 = (const float*)d_in[14];
  const float* pe_e_b2 = (const float*)d_in[15];
  const float* phi_w1 = (const float*)d_in[16];
  const float* phi_b1 = (const float*)d_in[17];
  const float* phi_w2 = (const float*)d_in[18];
  const float* phi_b2 = (const float*)d_in[19];
  const float* size_w1 = (const float*)d_in[20];
  const float* size_b1 = (const float*)d_in[21];
  const float* size_w2 = (const float*)d_in[22];
  const float* size_b2 = (const float*)d_in[23];
  const float* pe_d_w1 = (const float*)d_in[24];
  const float* pe_d_b1 = (const float*)d_in[25];
  const float* pe_d_g = (const float*)d_in[26];
  const float* pe_d_bt = (const float*)d_in[27];
  const float* pe_d_w2 = (const float*)d_in[28];
  const float* pe_d_b2 = (const float*)d_in[29];
  const float* dec_w1 = (const float*)d_in[30];
  const float* dec_b1 = (const float*)d_in[31];
  const float* dec_w2 = (const float*)d_in[32];
  const float* dec_b2 = (const float*)d_in[33];

  // ---- workspace (small, <11 MB) ----
  char* ws = (char*)d_ws;
  int* start = (int*)(ws);                                   // 131076 B
  double* mag = (double*)(ws + 0x40000);                     // 1 MB
  int* key = (int*)(ws + 0x140000);                          // 512 KB
  float* enc_tab = (float*)(ws + 0x1C0000);                  // 18x64 f32
  float* dec_tab = (float*)(ws + 0x1C2000);                  // 17x64 f32
  unsigned short* w1s = (unsigned short*)(ws + 0x1C4000);    // 12 KB
  unsigned short* w2s = (unsigned short*)(ws + 0x1C8000);    // 24 KB
  float* zbuf = (float*)(ws + 0x200000);                     // 8 MB (live during decoder)
  int* ndec = (int*)(ws + 0xA00000);                         // 128 KB

  float* out0 = (float*)d_out;
  float* out1 = out0 + 71303168;    // B*17*128
  float* out2 = out1 + 557056;      // B*17

  // y1/y2 scratch inside out0: consumed before k_decoder overwrites out0
  float* y1 = out0;                  // NELEM*64 f32 = 32 MB
  float* y2 = out0 + 8388608;        // B*64 f32 = 8 MB

  k_bounds<<<512, 256, 0, stream>>>(batch, start);
  k_mag<<<512, 256, 0, stream>>>(x, rank_w, rank_b, mag);
  k_rank<<<512, 256, 0, stream>>>(batch, start, mag, key);
  k_tables<<<1, 64, 0, stream>>>(pe_e_w1, pe_e_b1, pe_e_g, pe_e_bt, pe_e_w2, pe_e_b2,
                                 pe_d_w1, pe_d_b1, pe_d_g, pe_d_bt, pe_d_w2, pe_d_b2,
                                 enc_tab, dec_tab);
  k_prep_w<<<72, 256, 0, stream>>>(dec_w1, dec_w2, w1s, w2s);
  k_encoder<<<2048, 256, 0, stream>>>(x, batch, key, start, psi_w1, psi_b1, psi_g, psi_bt,
                                      psi_w2, psi_b2, enc_tab, y1);
  k_segsum<<<8192, 256, 0, stream>>>(y1, start, y2);
  k_phi<<<128, 256, 0, stream>>>(y2, start, phi_w1, phi_b1, phi_w2, phi_b2,
                                 size_w1, size_b1, size_w2, size_b2, zbuf, ndec);
  k_decoder<<<8704, 256, 0, stream>>>(zbuf, dec_tab, w1s, w2s, dec_b1, dec_b2, ndec, out0);
  k_outaux<<<2176, 256, 0, stream>>>(ndec, out1, out2);
}

// Round 3
// 689.304 us; speedup vs baseline: 1.0936x; 1.0936x over previous
//
#include <hip/hip_runtime.h>

#define NELEM 131072
#define BSETS 32768
#define DIM 128
#define HID 64
#define MAXP 17

typedef __attribute__((ext_vector_type(8))) short short8;
typedef __attribute__((ext_vector_type(4))) float f32x4;

__device__ __forceinline__ unsigned short f2bf(float f) {
  unsigned u = __float_as_uint(f);
  u += 0x7fff + ((u >> 16) & 1);   // RNE
  return (unsigned short)(u >> 16);
}

// ---------------- segment bounds from sorted batch (int32) ----------------
__global__ __launch_bounds__(256) void k_bounds(const int* __restrict__ batch,
                                                int* __restrict__ start) {
  int i = blockIdx.x * 256 + threadIdx.x;
  int b = batch[i];
  if (i == 0) {
    for (int bb = 0; bb <= b; ++bb) start[bb] = 0;
  } else {
    int bp = batch[i - 1];
    for (int bb = bp + 1; bb <= b; ++bb) start[bb] = i;
  }
  if (i == NELEM - 1) {
    for (int bb = b + 1; bb <= BSETS; ++bb) start[bb] = NELEM;
  }
}

// ---------------- rank scores: wave-per-row, coalesced float2, fp64 butterfly ----------------
__global__ __launch_bounds__(256) void k_mag(const float* __restrict__ x,
                                             const float* __restrict__ rank_w,
                                             const float* __restrict__ rank_b,
                                             double* __restrict__ mag) {
  int t = threadIdx.x;
  int lane = t & 63;
  int w = t >> 6;
  float2 wv = ((const float2*)rank_w)[lane];
  double w0 = wv.x, w1 = wv.y;
  double rb = rank_b[0];
  int rowbase = (blockIdx.x * 4 + w) * 32;
  for (int it = 0; it < 32; ++it) {
    int row = rowbase + it;
    float2 xv = ((const float2*)(x + (size_t)row * DIM))[lane];
    double acc = (double)xv.x * w0 + (double)xv.y * w1;
#pragma unroll
    for (int m = 1; m < 64; m <<= 1)
      acc += __shfl_xor(acc, m, 64);
    if (lane == 0) mag[row] = acc + rb;
  }
}

// ---------------- rank within segment (stable ascending) ----------------
__global__ __launch_bounds__(256) void k_rank(const int* __restrict__ batch,
                                              const int* __restrict__ start,
                                              const double* __restrict__ mag,
                                              int* __restrict__ key) {
  int i = blockIdx.x * 256 + threadIdx.x;
  int b = batch[i];
  int s = start[b], e = start[b + 1];
  double mi = mag[i];
  int r = 0;
  for (int j = s; j < e; ++j) {
    double mj = mag[j];
    r += (mj < mi) || (mj == mi && j < i);
  }
  key[i] = r;
}

// ---------------- positional-encoder tables (17->40 LN tanh ->64) ----------------
__device__ void pos_mlp40(int row, const float* w1, const float* b1, const float* g,
                          const float* bt, const float* w2, const float* b2, float* out) {
  float h[40];
  for (int j = 0; j < 40; ++j) h[j] = b1[j] + (row >= 0 ? w1[row * 40 + j] : 0.0f);
  float s = 0.f;
  for (int j = 0; j < 40; ++j) s += h[j];
  float mean = s * (1.0f / 40.0f);
  float v = 0.f;
  for (int j = 0; j < 40; ++j) { float d = h[j] - mean; v += d * d; }
  float rs = rsqrtf(v * (1.0f / 40.0f) + 1e-5f);
  float tb[40];
  for (int j = 0; j < 40; ++j) tb[j] = tanhf((h[j] - mean) * rs * g[j] + bt[j]);
  for (int o = 0; o < 64; ++o) {
    float a = b2[o];
    for (int j = 0; j < 40; ++j) a += tb[j] * w2[j * 64 + o];
    out[o] = a;
  }
}

__global__ void k_tables(const float* ew1, const float* eb1, const float* eg, const float* ebt,
                         const float* ew2, const float* eb2,
                         const float* dw1, const float* db1, const float* dg, const float* dbt,
                         const float* dw2, const float* db2,
                         float* enc_tab, float* dec_tab) {
  int t = threadIdx.x;
  if (t < 18) {
    float out[64];
    pos_mlp40(t < 17 ? t : -1, ew1, eb1, eg, ebt, ew2, eb2, out);
    for (int o = 0; o < 64; ++o) enc_tab[t * 64 + o] = out[o];
  } else if (t >= 32 && t < 49) {
    float out[64];
    pos_mlp40(t - 32, dw1, db1, dg, dbt, dw2, db2, out);
    for (int o = 0; o < 64; ++o) dec_tab[(t - 32) * 64 + o] = out[o];
  }
}

// ---------------- decoder weights -> bf16, MFMA-fragment-swizzled ----------------
__global__ __launch_bounds__(256) void k_prep_w(const float* __restrict__ w1,
                                                const float* __restrict__ w2,
                                                unsigned short* __restrict__ w1s,
                                                unsigned short* __restrict__ w2s) {
  int idx = blockIdx.x * 256 + threadIdx.x;
  if (idx < 6144) {   // dec_w1: 64x96, 2 ksteps x 6 ntiles
    int i = idx & 7, lane = (idx >> 3) & 63, rest = idx >> 9;
    int jt = rest % 6, s = rest / 6;
    int k = s * 32 + (lane >> 4) * 8 + i;
    int n = jt * 16 + (lane & 15);
    w1s[idx] = f2bf(w1[k * 96 + n]);
  }
  int idx2 = idx - 6144;
  if (idx2 >= 0 && idx2 < 12288) {  // dec_w2: 96x128, 3 ksteps x 8 ntiles
    int i = idx2 & 7, lane = (idx2 >> 3) & 63, rest = idx2 >> 9;
    int jt = rest % 8, s = rest / 8;
    int k = s * 32 + (lane >> 4) * 8 + i;
    int n = jt * 16 + (lane & 15);
    w2s[idx2] = f2bf(w2[k * 128 + n]);
  }
}

// ---------------- encoder: psi MLP (128->96 LN tanh ->64) * pe[rank] ----------------
__global__ __launch_bounds__(256) void k_encoder(
    const float* __restrict__ x, const int* __restrict__ batch,
    const int* __restrict__ key, const int* __restrict__ start,
    const float* __restrict__ w1, const float* __restrict__ b1,
    const float* __restrict__ g, const float* __restrict__ bt,
    const float* __restrict__ w2, const float* __restrict__ b2,
    const float* __restrict__ enc_tab, float* __restrict__ y1) {
  __shared__ float xt[64][129];
  __shared__ float tt[64][97];
  __shared__ float ps1[4][64];
  __shared__ float ps2[4][64];
  int t = threadIdx.x;
  int base = blockIdx.x * 64;
  const float4* xg = (const float4*)(x + (size_t)base * DIM);
#pragma unroll
  for (int v = 0; v < 8; ++v) {
    int f = t + 256 * v;
    float4 val = xg[f];
    int e = f >> 5, kq = (f & 31) * 4;
    xt[e][kq] = val.x; xt[e][kq + 1] = val.y; xt[e][kq + 2] = val.z; xt[e][kq + 3] = val.w;
  }
  __syncthreads();
  int lane = t & 63;
  int w = __builtin_amdgcn_readfirstlane(t >> 6);
  int j0 = w * 24;
  float acc[24];
#pragma unroll
  for (int jj = 0; jj < 24; ++jj) acc[jj] = b1[j0 + jj];
  for (int k = 0; k < DIM; ++k) {
    float xv = xt[lane][k];
#pragma unroll
    for (int jj = 0; jj < 24; ++jj) acc[jj] += xv * w1[k * 96 + j0 + jj];
  }
  float s1 = 0.f, s2 = 0.f;
#pragma unroll
  for (int jj = 0; jj < 24; ++jj) { s1 += acc[jj]; s2 += acc[jj] * acc[jj]; }
  ps1[w][lane] = s1; ps2[w][lane] = s2;
  __syncthreads();
  float S1 = ps1[0][lane] + ps1[1][lane] + ps1[2][lane] + ps1[3][lane];
  float S2 = ps2[0][lane] + ps2[1][lane] + ps2[2][lane] + ps2[3][lane];
  float mean = S1 * (1.0f / 96.0f);
  float var = S2 * (1.0f / 96.0f) - mean * mean;
  float rs = rsqrtf(var + 1e-5f);
#pragma unroll
  for (int jj = 0; jj < 24; ++jj) {
    float hv = (acc[jj] - mean) * rs * g[j0 + jj] + bt[j0 + jj];
    tt[lane][j0 + jj] = tanhf(hv);
  }
  __syncthreads();
  int o0 = w * 16;
  float acc2[16];
#pragma unroll
  for (int oo = 0; oo < 16; ++oo) acc2[oo] = b2[o0 + oo];
  for (int j = 0; j < 96; ++j) {
    float tv = tt[lane][j];
#pragma unroll
    for (int oo = 0; oo < 16; ++oo) acc2[oo] += tv * w2[j * 64 + o0 + oo];
  }
  int gi = base + lane;
  int kk = key[gi];
  int row = kk < MAXP ? kk : MAXP;
  int bb = batch[gi];
  int pos = start[bb] + kk;
  const float* pe = enc_tab + row * 64;
#pragma unroll
  for (int oo = 0; oo < 16; ++oo) acc2[oo] *= pe[o0 + oo];
  float4* d4 = (float4*)(y1 + (size_t)pos * 64 + o0);
#pragma unroll
  for (int q = 0; q < 4; ++q)
    d4[q] = make_float4(acc2[4 * q], acc2[4 * q + 1], acc2[4 * q + 2], acc2[4 * q + 3]);
}

// ---------------- deterministic per-segment sum ----------------
__global__ __launch_bounds__(256) void k_segsum(const float* __restrict__ y1,
                                                const int* __restrict__ start,
                                                float* __restrict__ y2) {
  int idx = blockIdx.x * 256 + threadIdx.x;
  int b = idx >> 6, o = idx & 63;
  int s = start[b], e = start[b + 1];
  float acc = 0.f;
  for (int p = s; p < e; ++p) acc += y1[(size_t)p * 64 + o];
  y2[idx] = acc;
}

// ---------------- phi MLP + size_pred + argmax: 64 sets/block cooperative ----------------
__global__ __launch_bounds__(256) void k_phi(const float* __restrict__ y2,
                                             const int* __restrict__ start,
                                             const float* __restrict__ w1, const float* __restrict__ b1,
                                             const float* __restrict__ w2, const float* __restrict__ b2,
                                             const float* __restrict__ sw1, const float* __restrict__ sb1,
                                             const float* __restrict__ sw2, const float* __restrict__ sb2,
                                             float* __restrict__ z, int* __restrict__ ndec) {
  __shared__ float yt[64][65];
  __shared__ float tt[64][73];
  __shared__ float zt[64][65];
  __shared__ float st[64][41];
  int t = threadIdx.x;
  int base = blockIdx.x * 64;
  const float4* yg = (const float4*)(y2 + (size_t)base * 64);
#pragma unroll
  for (int v = 0; v < 4; ++v) {     // stage 64x64 f32 coalesced
    int f = t + 256 * v;
    float4 val = yg[f];
    int e = f >> 4, kq = (f & 15) * 4;
    yt[e][kq] = val.x; yt[e][kq + 1] = val.y; yt[e][kq + 2] = val.z; yt[e][kq + 3] = val.w;
  }
  __syncthreads();
  int lane = t & 63;
  int w = __builtin_amdgcn_readfirstlane(t >> 6);
  int sb = base + lane;
  int nb = start[sb + 1] - start[sb];
  // layer1: 72 hidden = 4 waves x 18
  int j0 = w * 18;
  float acc[18];
#pragma unroll
  for (int jj = 0; jj < 18; ++jj) acc[jj] = b1[j0 + jj];
  for (int k = 0; k < 64; ++k) {
    float yv = yt[lane][k];
#pragma unroll
    for (int jj = 0; jj < 18; ++jj) acc[jj] += yv * w1[k * 72 + j0 + jj];
  }
  if (nb < MAXP) {
    const float* wr = w1 + (64 + nb) * 72 + j0;
#pragma unroll
    for (int jj = 0; jj < 18; ++jj) acc[jj] += wr[jj];
  }
#pragma unroll
  for (int jj = 0; jj < 18; ++jj) tt[lane][j0 + jj] = tanhf(acc[jj]);
  __syncthreads();
  // layer2: 64 out = 4 waves x 16
  int o0 = w * 16;
  float acc2[16];
#pragma unroll
  for (int oo = 0; oo < 16; ++oo) acc2[oo] = b2[o0 + oo];
  for (int j = 0; j < 72; ++j) {
    float tv = tt[lane][j];
#pragma unroll
    for (int oo = 0; oo < 16; ++oo) acc2[oo] += tv * w2[j * 64 + o0 + oo];
  }
  float4* zd = (float4*)(z + (size_t)sb * 64 + o0);
#pragma unroll
  for (int q = 0; q < 4; ++q)
    zd[q] = make_float4(acc2[4 * q], acc2[4 * q + 1], acc2[4 * q + 2], acc2[4 * q + 3]);
#pragma unroll
  for (int oo = 0; oo < 16; ++oo) zt[lane][o0 + oo] = acc2[oo];
  __syncthreads();
  // size_pred layer1: 40 hidden = 4 waves x 10
  int s0 = w * 10;
  float hs[10];
#pragma unroll
  for (int jj = 0; jj < 10; ++jj) hs[jj] = sb1[s0 + jj];
  for (int o = 0; o < 64; ++o) {
    float v = zt[lane][o];
#pragma unroll
    for (int jj = 0; jj < 10; ++jj) hs[jj] += v * sw1[o * 40 + s0 + jj];
  }
#pragma unroll
  for (int jj = 0; jj < 10; ++jj) st[lane][s0 + jj] = tanhf(hs[jj]);
  __syncthreads();
  // logits + argmax: wave 0 only
  if (w == 0) {
    float lg[17];
#pragma unroll
    for (int l = 0; l < 17; ++l) lg[l] = sb2[l];
    for (int j = 0; j < 40; ++j) {
      float tv = st[lane][j];
#pragma unroll
      for (int l = 0; l < 17; ++l) lg[l] += tv * sw2[j * 17 + l];
    }
    float best = lg[0]; int bi = 0;
#pragma unroll
    for (int l = 1; l < 17; ++l) if (lg[l] > best) { best = lg[l]; bi = l; }
    ndec[sb] = bi;
  }
}

// ---------------- decoder: zp(64) -> 96 tanh -> 128, bf16 MFMA ----------------
__global__ __launch_bounds__(256) void k_decoder(
    const float* __restrict__ z, const float* __restrict__ dec_tab,
    const unsigned short* __restrict__ w1s, const unsigned short* __restrict__ w2s,
    const float* __restrict__ b1, const float* __restrict__ b2,
    const int* __restrict__ ndec, float* __restrict__ out0) {
  __shared__ __align__(16) unsigned short h2[64][104];
  int t = threadIdx.x;
  int lane = t & 63;
  int w = __builtin_amdgcn_readfirstlane(t >> 6);
  int quad = lane >> 4, m = lane & 15;
  int r = blockIdx.x * 64 + w * 16 + m;
  int b = r / 17, p = r - b * 17;
  const float* zr = z + (size_t)b * 64;
  const float* per = dec_tab + p * 64;
  short8 a1[2];
#pragma unroll
  for (int s = 0; s < 2; ++s) {
    int k0 = s * 32 + quad * 8;
#pragma unroll
    for (int i = 0; i < 8; ++i) {
      float v = zr[k0 + i] * per[k0 + i];
      ((unsigned short*)&a1[s])[i] = f2bf(v);
    }
  }
  const short8* w1f = (const short8*)w1s;
  f32x4 acc[6] = {};
#pragma unroll
  for (int jt = 0; jt < 6; ++jt) {
    acc[jt] = __builtin_amdgcn_mfma_f32_16x16x32_bf16(a1[0], w1f[jt * 64 + lane], acc[jt], 0, 0, 0);
    acc[jt] = __builtin_amdgcn_mfma_f32_16x16x32_bf16(a1[1], w1f[(6 + jt) * 64 + lane], acc[jt], 0, 0, 0);
  }
#pragma unroll
  for (int jt = 0; jt < 6; ++jt) {
    int col = jt * 16 + m;
    float bias = b1[col];
#pragma unroll
    for (int reg = 0; reg < 4; ++reg) {
      int rl = w * 16 + quad * 4 + reg;
      h2[rl][col] = f2bf(tanhf(acc[jt][reg] + bias));
    }
  }
  __syncthreads();
  short8 a2[3];
#pragma unroll
  for (int s = 0; s < 3; ++s)
    a2[s] = *(const short8*)&h2[w * 16 + m][s * 32 + quad * 8];
  const short8* w2f = (const short8*)w2s;
  f32x4 acc2[8] = {};
#pragma unroll
  for (int nt = 0; nt < 8; ++nt) {
#pragma unroll
    for (int s = 0; s < 3; ++s)
      acc2[nt] = __builtin_amdgcn_mfma_f32_16x16x32_bf16(a2[s], w2f[(s * 8 + nt) * 64 + lane], acc2[nt], 0, 0, 0);
  }
#pragma unroll
  for (int nt = 0; nt < 8; ++nt) {
    int n = nt * 16 + m;
    float bias = b2[n];
#pragma unroll
    for (int reg = 0; reg < 4; ++reg) {
      int rl = w * 16 + quad * 4 + reg;
      int rg = blockIdx.x * 64 + rl;
      int bb = rg / 17, pp = rg - bb * 17;
      float v = acc2[nt][reg] + bias;
      if (pp >= ndec[bb]) v = 0.0f;
      out0[(size_t)rg * 128 + n] = v;
    }
  }
}

// ---------------- aux outputs ----------------
__global__ __launch_bounds__(256) void k_outaux(const int* __restrict__ ndec,
                                                float* __restrict__ out1,
                                                float* __restrict__ out2) {
  int r = blockIdx.x * 256 + threadIdx.x;
  int b = r / 17, p = r - b * 17;
  out1[r] = (float)b;
  out2[r] = (p < ndec[b]) ? 1.0f : 0.0f;
}

extern "C" void kernel_launch(void* const* d_in, const int* in_sizes, int n_in,
                              void* d_out, int out_size, void* d_ws, size_t ws_size,
                              hipStream_t stream) {
  const float* x = (const float*)d_in[0];
  const int* batch = (const int*)d_in[1];
  const float* rank_w = (const float*)d_in[2];
  const float* rank_b = (const float*)d_in[3];
  const float* psi_w1 = (const float*)d_in[4];
  const float* psi_b1 = (const float*)d_in[5];
  const float* psi_g = (const float*)d_in[6];
  const float* psi_bt = (const float*)d_in[7];
  const float* psi_w2 = (const float*)d_in[8];
  const float* psi_b2 = (const float*)d_in[9];
  const float* pe_e_w1 = (const float*)d_in[10];
  const float* pe_e_b1 = (const float*)d_in[11];
  const float* pe_e_g = (const float*)d_in[12];
  const float* pe_e_bt = (const float*)d_in[13];
  const float* pe_e_w2 = (const float*)d_in[14];
  const float* pe_e_b2 = (const float*)d_in[15];
  const float* phi_w1 = (const float*)d_in[16];
  const float* phi_b1 = (const float*)d_in[17];
  const float* phi_w2 = (const float*)d_in[18];
  const float* phi_b2 = (const float*)d_in[19];
  const float* size_w1 = (const float*)d_in[20];
  const float* size_b1 = (const float*)d_in[21];
  const float* size_w2 = (const float*)d_in[22];
  const float* size_b2 = (const float*)d_in[23];
  const float* pe_d_w1 = (const float*)d_in[24];
  const float* pe_d_b1 = (const float*)d_in[25];
  const float* pe_d_g = (const float*)d_in[26];
  const float* pe_d_bt = (const float*)d_in[27];
  const float* pe_d_w2 = (const float*)d_in[28];
  const float* pe_d_b2 = (const float*)d_in[29];
  const float* dec_w1 = (const float*)d_in[30];
  const float* dec_b1 = (const float*)d_in[31];
  const float* dec_w2 = (const float*)d_in[32];
  const float* dec_b2 = (const float*)d_in[33];

  char* ws = (char*)d_ws;
  int* start = (int*)(ws);                                   // 131076 B
  double* mag = (double*)(ws + 0x40000);                     // 1 MB
  int* key = (int*)(ws + 0x140000);                          // 512 KB
  float* enc_tab = (float*)(ws + 0x1C0000);
  float* dec_tab = (float*)(ws + 0x1C2000);
  unsigned short* w1s = (unsigned short*)(ws + 0x1C4000);
  unsigned short* w2s = (unsigned short*)(ws + 0x1C8000);
  float* zbuf = (float*)(ws + 0x200000);                     // 8 MB (live during decoder)
  int* ndec = (int*)(ws + 0xA00000);                         // 128 KB

  float* out0 = (float*)d_out;
  float* out1 = out0 + 71303168;    // B*17*128
  float* out2 = out1 + 557056;      // B*17

  // y1/y2 scratch inside out0: consumed before k_decoder overwrites out0
  float* y1 = out0;                  // NELEM*64 f32 = 32 MB
  float* y2 = out0 + 8388608;        // B*64 f32 = 8 MB

  k_bounds<<<512, 256, 0, stream>>>(batch, start);
  k_mag<<<1024, 256, 0, stream>>>(x, rank_w, rank_b, mag);
  k_rank<<<512, 256, 0, stream>>>(batch, start, mag, key);
  k_tables<<<1, 64, 0, stream>>>(pe_e_w1, pe_e_b1, pe_e_g, pe_e_bt, pe_e_w2, pe_e_b2,
                                 pe_d_w1, pe_d_b1, pe_d_g, pe_d_bt, pe_d_w2, pe_d_b2,
                                 enc_tab, dec_tab);
  k_prep_w<<<72, 256, 0, stream>>>(dec_w1, dec_w2, w1s, w2s);
  k_encoder<<<2048, 256, 0, stream>>>(x, batch, key, start, psi_w1, psi_b1, psi_g, psi_bt,
                                      psi_w2, psi_b2, enc_tab, y1);
  k_segsum<<<8192, 256, 0, stream>>>(y1, start, y2);
  k_phi<<<512, 256, 0, stream>>>(y2, start, phi_w1, phi_b1, phi_w2, phi_b2,
                                 size_w1, size_b1, size_w2, size_b2, zbuf, ndec);
  k_decoder<<<8704, 256, 0, stream>>>(zbuf, dec_tab, w1s, w2s, dec_b1, dec_b2, ndec, out0);
  k_outaux<<<2176, 256, 0, stream>>>(ndec, out1, out2);
}

// Round 4
// 642.875 us; speedup vs baseline: 1.1726x; 1.0722x over previous
//
#include <hip/hip_runtime.h>

#define NELEM 131072
#define BSETS 32768
#define DIM 128
#define HID 64
#define MAXP 17

typedef __attribute__((ext_vector_type(8))) short short8;
typedef __attribute__((ext_vector_type(4))) float f32x4;

__device__ __forceinline__ unsigned short f2bf(float f) {
  unsigned u = __float_as_uint(f);
  u += 0x7fff + ((u >> 16) & 1);   // RNE
  return (unsigned short)(u >> 16);
}

// ---------------- positional-encoder tables (17->40 LN tanh ->64) ----------------
__device__ void pos_mlp40(int row, const float* w1, const float* b1, const float* g,
                          const float* bt, const float* w2, const float* b2, float* out) {
  float h[40];
  for (int j = 0; j < 40; ++j) h[j] = b1[j] + (row >= 0 ? w1[row * 40 + j] : 0.0f);
  float s = 0.f;
  for (int j = 0; j < 40; ++j) s += h[j];
  float mean = s * (1.0f / 40.0f);
  float v = 0.f;
  for (int j = 0; j < 40; ++j) { float d = h[j] - mean; v += d * d; }
  float rs = rsqrtf(v * (1.0f / 40.0f) + 1e-5f);
  float tb[40];
  for (int j = 0; j < 40; ++j) tb[j] = tanhf((h[j] - mean) * rs * g[j] + bt[j]);
  for (int o = 0; o < 64; ++o) {
    float a = b2[o];
    for (int j = 0; j < 40; ++j) a += tb[j] * w2[j * 64 + o];
    out[o] = a;
  }
}

// ---------------- fused init: mag | bounds | pe tables | weight swizzle ----------------
__global__ __launch_bounds__(256) void k_init(
    const float* __restrict__ x, const int* __restrict__ batch,
    const float* __restrict__ rank_w, const float* __restrict__ rank_b,
    double* __restrict__ mag, int* __restrict__ start,
    const float* ew1, const float* eb1, const float* eg, const float* ebt,
    const float* ew2, const float* eb2,
    const float* dw1, const float* db1, const float* dg, const float* dbt,
    const float* dw2, const float* db2,
    float* enc_tab, float* dec_tab,
    const float* __restrict__ decw1, const float* __restrict__ decw2,
    unsigned short* __restrict__ w1s, unsigned short* __restrict__ w2s) {
  int blk = blockIdx.x;
  int t = threadIdx.x;
  if (blk < 1024) {                       // ---- mag: wave-per-row, fp64 butterfly ----
    int lane = t & 63;
    int w = t >> 6;
    float2 wv = ((const float2*)rank_w)[lane];
    double w0 = wv.x, w1 = wv.y;
    double rb = rank_b[0];
    int rowbase = (blk * 4 + w) * 32;
    for (int it = 0; it < 32; ++it) {
      int row = rowbase + it;
      float2 xv = ((const float2*)(x + (size_t)row * DIM))[lane];
      double acc = (double)xv.x * w0 + (double)xv.y * w1;
#pragma unroll
      for (int m = 1; m < 64; m <<= 1)
        acc += __shfl_xor(acc, m, 64);
      if (lane == 0) mag[row] = acc + rb;
    }
  } else if (blk < 1536) {                // ---- bounds ----
    int i = (blk - 1024) * 256 + t;
    int b = batch[i];
    if (i == 0) {
      for (int bb = 0; bb <= b; ++bb) start[bb] = 0;
    } else {
      int bp = batch[i - 1];
      for (int bb = bp + 1; bb <= b; ++bb) start[bb] = i;
    }
    if (i == NELEM - 1) {
      for (int bb = b + 1; bb <= BSETS; ++bb) start[bb] = NELEM;
    }
  } else if (blk == 1536) {               // ---- pe tables ----
    if (t < 18) {
      float out[64];
      pos_mlp40(t < 17 ? t : -1, ew1, eb1, eg, ebt, ew2, eb2, out);
      for (int o = 0; o < 64; ++o) enc_tab[t * 64 + o] = out[o];
    } else if (t >= 32 && t < 49) {
      float out[64];
      pos_mlp40(t - 32, dw1, db1, dg, dbt, dw2, db2, out);
      for (int o = 0; o < 64; ++o) dec_tab[(t - 32) * 64 + o] = out[o];
    }
  } else {                                // ---- decoder weight swizzle ----
    int idx = (blk - 1537) * 256 + t;
    if (idx < 6144) {   // dec_w1: 64x96, 2 ksteps x 6 ntiles
      int i = idx & 7, lane = (idx >> 3) & 63, rest = idx >> 9;
      int jt = rest % 6, s = rest / 6;
      int k = s * 32 + (lane >> 4) * 8 + i;
      int n = jt * 16 + (lane & 15);
      w1s[idx] = f2bf(decw1[k * 96 + n]);
    }
    int idx2 = idx - 6144;
    if (idx2 >= 0 && idx2 < 12288) {  // dec_w2: 96x128, 3 ksteps x 8 ntiles
      int i = idx2 & 7, lane = (idx2 >> 3) & 63, rest = idx2 >> 9;
      int jt = rest % 8, s = rest / 8;
      int k = s * 32 + (lane >> 4) * 8 + i;
      int n = jt * 16 + (lane & 15);
      w2s[idx2] = f2bf(decw2[k * 128 + n]);
    }
  }
}

// ---------------- rank within segment (stable ascending) ----------------
__global__ __launch_bounds__(256) void k_rank(const int* __restrict__ batch,
                                              const int* __restrict__ start,
                                              const double* __restrict__ mag,
                                              int* __restrict__ key) {
  int i = blockIdx.x * 256 + threadIdx.x;
  int b = batch[i];
  int s = start[b], e = start[b + 1];
  double mi = mag[i];
  int r = 0;
  for (int j = s; j < e; ++j) {
    double mj = mag[j];
    r += (mj < mi) || (mj == mi && j < i);
  }
  key[i] = r;
}

// ---------------- encoder: psi MLP (128->96 LN tanh ->64) * pe[rank] ----------------
__global__ __launch_bounds__(256) void k_encoder(
    const float* __restrict__ x, const int* __restrict__ batch,
    const int* __restrict__ key, const int* __restrict__ start,
    const float* __restrict__ w1, const float* __restrict__ b1,
    const float* __restrict__ g, const float* __restrict__ bt,
    const float* __restrict__ w2, const float* __restrict__ b2,
    const float* __restrict__ enc_tab, float* __restrict__ y1) {
  __shared__ float xt[64][129];
  __shared__ float tt[64][97];
  __shared__ float ps1[4][64];
  __shared__ float ps2[4][64];
  int t = threadIdx.x;
  int base = blockIdx.x * 64;
  const float4* xg = (const float4*)(x + (size_t)base * DIM);
#pragma unroll
  for (int v = 0; v < 8; ++v) {
    int f = t + 256 * v;
    float4 val = xg[f];
    int e = f >> 5, kq = (f & 31) * 4;
    xt[e][kq] = val.x; xt[e][kq + 1] = val.y; xt[e][kq + 2] = val.z; xt[e][kq + 3] = val.w;
  }
  __syncthreads();
  int lane = t & 63;
  int w = __builtin_amdgcn_readfirstlane(t >> 6);
  int j0 = w * 24;
  float acc[24];
#pragma unroll
  for (int jj = 0; jj < 24; ++jj) acc[jj] = b1[j0 + jj];
  for (int k = 0; k < DIM; ++k) {
    float xv = xt[lane][k];
#pragma unroll
    for (int jj = 0; jj < 24; ++jj) acc[jj] += xv * w1[k * 96 + j0 + jj];
  }
  float s1 = 0.f, s2 = 0.f;
#pragma unroll
  for (int jj = 0; jj < 24; ++jj) { s1 += acc[jj]; s2 += acc[jj] * acc[jj]; }
  ps1[w][lane] = s1; ps2[w][lane] = s2;
  __syncthreads();
  float S1 = ps1[0][lane] + ps1[1][lane] + ps1[2][lane] + ps1[3][lane];
  float S2 = ps2[0][lane] + ps2[1][lane] + ps2[2][lane] + ps2[3][lane];
  float mean = S1 * (1.0f / 96.0f);
  float var = S2 * (1.0f / 96.0f) - mean * mean;
  float rs = rsqrtf(var + 1e-5f);
#pragma unroll
  for (int jj = 0; jj < 24; ++jj) {
    float hv = (acc[jj] - mean) * rs * g[j0 + jj] + bt[j0 + jj];
    tt[lane][j0 + jj] = tanhf(hv);
  }
  __syncthreads();
  int o0 = w * 16;
  float acc2[16];
#pragma unroll
  for (int oo = 0; oo < 16; ++oo) acc2[oo] = b2[o0 + oo];
  for (int j = 0; j < 96; ++j) {
    float tv = tt[lane][j];
#pragma unroll
    for (int oo = 0; oo < 16; ++oo) acc2[oo] += tv * w2[j * 64 + o0 + oo];
  }
  int gi = base + lane;
  int kk = key[gi];
  int row = kk < MAXP ? kk : MAXP;
  int bb = batch[gi];
  int pos = start[bb] + kk;
  const float* pe = enc_tab + row * 64;
#pragma unroll
  for (int oo = 0; oo < 16; ++oo) acc2[oo] *= pe[o0 + oo];
  float4* d4 = (float4*)(y1 + (size_t)pos * 64 + o0);
#pragma unroll
  for (int q = 0; q < 4; ++q)
    d4[q] = make_float4(acc2[4 * q], acc2[4 * q + 1], acc2[4 * q + 2], acc2[4 * q + 3]);
}

// ---------------- phi (+fused segment-sum) + size_pred + argmax: 64 sets/block ----------------
__global__ __launch_bounds__(256) void k_phi(const float* __restrict__ y1,
                                             const int* __restrict__ start,
                                             const float* __restrict__ w1, const float* __restrict__ b1,
                                             const float* __restrict__ w2, const float* __restrict__ b2,
                                             const float* __restrict__ sw1, const float* __restrict__ sb1,
                                             const float* __restrict__ sw2, const float* __restrict__ sb2,
                                             float* __restrict__ z, int* __restrict__ ndec) {
  __shared__ float yt[64][65];
  __shared__ float tt[64][73];
  __shared__ float zt[64][65];
  __shared__ float st[64][41];
  int t = threadIdx.x;
  int base = blockIdx.x * 64;
  {  // fused segment sum: thread (set s = t>>2, chunk c = t&3), ascending-p order
    int s = t >> 2, c = t & 3;
    int sb = base + s;
    int ps = start[sb], pe = start[sb + 1];
    float acc[16];
#pragma unroll
    for (int i = 0; i < 16; ++i) acc[i] = 0.f;
    for (int p = ps; p < pe; ++p) {
      const float4* row = (const float4*)(y1 + (size_t)p * 64 + c * 16);
#pragma unroll
      for (int q = 0; q < 4; ++q) {
        float4 v = row[q];
        acc[4 * q] += v.x; acc[4 * q + 1] += v.y; acc[4 * q + 2] += v.z; acc[4 * q + 3] += v.w;
      }
    }
#pragma unroll
    for (int i = 0; i < 16; ++i) yt[s][c * 16 + i] = acc[i];
  }
  __syncthreads();
  int lane = t & 63;
  int w = __builtin_amdgcn_readfirstlane(t >> 6);
  int sb = base + lane;
  int nb = start[sb + 1] - start[sb];
  // layer1: 72 hidden = 4 waves x 18
  int j0 = w * 18;
  float acc[18];
#pragma unroll
  for (int jj = 0; jj < 18; ++jj) acc[jj] = b1[j0 + jj];
  for (int k = 0; k < 64; ++k) {
    float yv = yt[lane][k];
#pragma unroll
    for (int jj = 0; jj < 18; ++jj) acc[jj] += yv * w1[k * 72 + j0 + jj];
  }
  if (nb < MAXP) {
    const float* wr = w1 + (64 + nb) * 72 + j0;
#pragma unroll
    for (int jj = 0; jj < 18; ++jj) acc[jj] += wr[jj];
  }
#pragma unroll
  for (int jj = 0; jj < 18; ++jj) tt[lane][j0 + jj] = tanhf(acc[jj]);
  __syncthreads();
  // layer2: 64 out = 4 waves x 16
  int o0 = w * 16;
  float acc2[16];
#pragma unroll
  for (int oo = 0; oo < 16; ++oo) acc2[oo] = b2[o0 + oo];
  for (int j = 0; j < 72; ++j) {
    float tv = tt[lane][j];
#pragma unroll
    for (int oo = 0; oo < 16; ++oo) acc2[oo] += tv * w2[j * 64 + o0 + oo];
  }
  float4* zd = (float4*)(z + (size_t)sb * 64 + o0);
#pragma unroll
  for (int q = 0; q < 4; ++q)
    zd[q] = make_float4(acc2[4 * q], acc2[4 * q + 1], acc2[4 * q + 2], acc2[4 * q + 3]);
#pragma unroll
  for (int oo = 0; oo < 16; ++oo) zt[lane][o0 + oo] = acc2[oo];
  __syncthreads();
  // size_pred layer1: 40 hidden = 4 waves x 10
  int s0 = w * 10;
  float hs[10];
#pragma unroll
  for (int jj = 0; jj < 10; ++jj) hs[jj] = sb1[s0 + jj];
  for (int o = 0; o < 64; ++o) {
    float v = zt[lane][o];
#pragma unroll
    for (int jj = 0; jj < 10; ++jj) hs[jj] += v * sw1[o * 40 + s0 + jj];
  }
#pragma unroll
  for (int jj = 0; jj < 10; ++jj) st[lane][s0 + jj] = tanhf(hs[jj]);
  __syncthreads();
  // logits + argmax: wave 0 only
  if (w == 0) {
    float lg[17];
#pragma unroll
    for (int l = 0; l < 17; ++l) lg[l] = sb2[l];
    for (int j = 0; j < 40; ++j) {
      float tv = st[lane][j];
#pragma unroll
      for (int l = 0; l < 17; ++l) lg[l] += tv * sw2[j * 17 + l];
    }
    float best = lg[0]; int bi = 0;
#pragma unroll
    for (int l = 1; l < 17; ++l) if (lg[l] > best) { best = lg[l]; bi = l; }
    ndec[sb] = bi;
  }
}

// ---------------- decoder (+fused aux outputs): zp(64)->96 tanh->128, bf16 MFMA ----------------
__global__ __launch_bounds__(256) void k_decoder(
    const float* __restrict__ z, const float* __restrict__ dec_tab,
    const unsigned short* __restrict__ w1s, const unsigned short* __restrict__ w2s,
    const float* __restrict__ b1, const float* __restrict__ b2,
    const int* __restrict__ ndec, float* __restrict__ out0,
    float* __restrict__ out1, float* __restrict__ out2) {
  __shared__ __align__(16) unsigned short h2[64][104];
  int t = threadIdx.x;
  int lane = t & 63;
  int w = __builtin_amdgcn_readfirstlane(t >> 6);
  int quad = lane >> 4, m = lane & 15;
  int r = blockIdx.x * 64 + w * 16 + m;
  int b = r / 17, p = r - b * 17;
  const float* zr = z + (size_t)b * 64;
  const float* per = dec_tab + p * 64;
  short8 a1[2];
#pragma unroll
  for (int s = 0; s < 2; ++s) {
    int k0 = s * 32 + quad * 8;
#pragma unroll
    for (int i = 0; i < 8; ++i) {
      float v = zr[k0 + i] * per[k0 + i];
      ((unsigned short*)&a1[s])[i] = f2bf(v);
    }
  }
  const short8* w1f = (const short8*)w1s;
  f32x4 acc[6] = {};
#pragma unroll
  for (int jt = 0; jt < 6; ++jt) {
    acc[jt] = __builtin_amdgcn_mfma_f32_16x16x32_bf16(a1[0], w1f[jt * 64 + lane], acc[jt], 0, 0, 0);
    acc[jt] = __builtin_amdgcn_mfma_f32_16x16x32_bf16(a1[1], w1f[(6 + jt) * 64 + lane], acc[jt], 0, 0, 0);
  }
#pragma unroll
  for (int jt = 0; jt < 6; ++jt) {
    int col = jt * 16 + m;
    float bias = b1[col];
#pragma unroll
    for (int reg = 0; reg < 4; ++reg) {
      int rl = w * 16 + quad * 4 + reg;
      h2[rl][col] = f2bf(tanhf(acc[jt][reg] + bias));
    }
  }
  __syncthreads();
  short8 a2[3];
#pragma unroll
  for (int s = 0; s < 3; ++s)
    a2[s] = *(const short8*)&h2[w * 16 + m][s * 32 + quad * 8];
  const short8* w2f = (const short8*)w2s;
  f32x4 acc2[8] = {};
#pragma unroll
  for (int nt = 0; nt < 8; ++nt) {
#pragma unroll
    for (int s = 0; s < 3; ++s)
      acc2[nt] = __builtin_amdgcn_mfma_f32_16x16x32_bf16(a2[s], w2f[(s * 8 + nt) * 64 + lane], acc2[nt], 0, 0, 0);
  }
#pragma unroll
  for (int nt = 0; nt < 8; ++nt) {
    int n = nt * 16 + m;
    float bias = b2[n];
#pragma unroll
    for (int reg = 0; reg < 4; ++reg) {
      int rl = w * 16 + quad * 4 + reg;
      int rg = blockIdx.x * 64 + rl;
      int bb = rg / 17, pp = rg - bb * 17;
      float v = acc2[nt][reg] + bias;
      if (pp >= ndec[bb]) v = 0.0f;
      out0[(size_t)rg * 128 + n] = v;
    }
  }
  if (t < 64) {   // fused aux outputs for this block's 64 rows
    int rg = blockIdx.x * 64 + t;
    int bb = rg / 17, pp = rg - bb * 17;
    out1[rg] = (float)bb;
    out2[rg] = (pp < ndec[bb]) ? 1.0f : 0.0f;
  }
}

extern "C" void kernel_launch(void* const* d_in, const int* in_sizes, int n_in,
                              void* d_out, int out_size, void* d_ws, size_t ws_size,
                              hipStream_t stream) {
  const float* x = (const float*)d_in[0];
  const int* batch = (const int*)d_in[1];
  const float* rank_w = (const float*)d_in[2];
  const float* rank_b = (const float*)d_in[3];
  const float* psi_w1 = (const float*)d_in[4];
  const float* psi_b1 = (const float*)d_in[5];
  const float* psi_g = (const float*)d_in[6];
  const float* psi_bt = (const float*)d_in[7];
  const float* psi_w2 = (const float*)d_in[8];
  const float* psi_b2 = (const float*)d_in[9];
  const float* pe_e_w1 = (const float*)d_in[10];
  const float* pe_e_b1 = (const float*)d_in[11];
  const float* pe_e_g = (const float*)d_in[12];
  const float* pe_e_bt = (const float*)d_in[13];
  const float* pe_e_w2 = (const float*)d_in[14];
  const float* pe_e_b2 = (const float*)d_in[15];
  const float* phi_w1 = (const float*)d_in[16];
  const float* phi_b1 = (const float*)d_in[17];
  const float* phi_w2 = (const float*)d_in[18];
  const float* phi_b2 = (const float*)d_in[19];
  const float* size_w1 = (const float*)d_in[20];
  const float* size_b1 = (const float*)d_in[21];
  const float* size_w2 = (const float*)d_in[22];
  const float* size_b2 = (const float*)d_in[23];
  const float* pe_d_w1 = (const float*)d_in[24];
  const float* pe_d_b1 = (const float*)d_in[25];
  const float* pe_d_g = (const float*)d_in[26];
  const float* pe_d_bt = (const float*)d_in[27];
  const float* pe_d_w2 = (const float*)d_in[28];
  const float* pe_d_b2 = (const float*)d_in[29];
  const float* dec_w1 = (const float*)d_in[30];
  const float* dec_b1 = (const float*)d_in[31];
  const float* dec_w2 = (const float*)d_in[32];
  const float* dec_b2 = (const float*)d_in[33];

  char* ws = (char*)d_ws;
  int* start = (int*)(ws);                                   // 131076 B
  double* mag = (double*)(ws + 0x40000);                     // 1 MB
  int* key = (int*)(ws + 0x140000);                          // 512 KB
  float* enc_tab = (float*)(ws + 0x1C0000);
  float* dec_tab = (float*)(ws + 0x1C2000);
  unsigned short* w1s = (unsigned short*)(ws + 0x1C4000);
  unsigned short* w2s = (unsigned short*)(ws + 0x1C8000);
  float* zbuf = (float*)(ws + 0x200000);                     // 8 MB (live during decoder)
  int* ndec = (int*)(ws + 0xA00000);                         // 128 KB

  float* out0 = (float*)d_out;
  float* out1 = out0 + 71303168;    // B*17*128
  float* out2 = out1 + 557056;      // B*17

  // y1 scratch inside out0: consumed by k_phi before k_decoder overwrites out0
  float* y1 = out0;                  // NELEM*64 f32 = 32 MB

  k_init<<<1609, 256, 0, stream>>>(x, batch, rank_w, rank_b, mag, start,
                                   pe_e_w1, pe_e_b1, pe_e_g, pe_e_bt, pe_e_w2, pe_e_b2,
                                   pe_d_w1, pe_d_b1, pe_d_g, pe_d_bt, pe_d_w2, pe_d_b2,
                                   enc_tab, dec_tab, dec_w1, dec_w2, w1s, w2s);
  k_rank<<<512, 256, 0, stream>>>(batch, start, mag, key);
  k_encoder<<<2048, 256, 0, stream>>>(x, batch, key, start, psi_w1, psi_b1, psi_g, psi_bt,
                                      psi_w2, psi_b2, enc_tab, y1);
  k_phi<<<512, 256, 0, stream>>>(y1, start, phi_w1, phi_b1, phi_w2, phi_b2,
                                 size_w1, size_b1, size_w2, size_b2, zbuf, ndec);
  k_decoder<<<8704, 256, 0, stream>>>(zbuf, dec_tab, w1s, w2s, dec_b1, dec_b2, ndec,
                                      out0, out1, out2);
}